// Round 6
// baseline (848.558 us; speedup 1.0000x reference)
//
#include <hip/hip_runtime.h>
#include <stdint.h>

// Problem constants
#define N_ROWS 8192
#define D_DIM  1024
#define M_CENT 20000
#define M_PAD  20224          // 79 * 256
#define M_TILES 79            // 256-wide center tiles
#define Y_DIM  256
#define BM 64                 // rows of X per block
#define BN 256                // centers per M-iteration (wave tile 64x64)
#define MSPLIT 8
#define TILES_PER_SPLIT 10    // ceil(79/8)
#define NKT 32                // K=1024 / 32 per MFMA step
#define GKT 8                 // kt per staged X group
#define NG  4                 // groups per mt
#define PANEL_X (NKT * 512)   // 16 rows x 1024 k, frag-packed
#define NKT_M 632             // M_PAD / 32
#define PANEL_W (NKT_M * 512) // 16 y-cols x M_PAD, frag-packed

// Fragment-linear packing: element (row,k) of a 16-row panel lives at
//   panel*PANEL + (k>>5)*512 + ((k>>3)&3)*128 + (row&15)*8 + (k&7)
// so a wave's MFMA fragment is one contiguous coalesced 1KB block.

typedef __attribute__((ext_vector_type(4))) float  f32x4;
typedef __attribute__((ext_vector_type(8))) __bf16 bf16x8;

__device__ __forceinline__ unsigned short f2bf(float f) {
    union { float f; unsigned u; } v; v.f = f;
    unsigned u = v.u;
    u += 0x7FFFu + ((u >> 16) & 1u);   // RNE
    return (unsigned short)(u >> 16);
}

__device__ __forceinline__ void gll16(void* lds, const void* g) {
    __builtin_amdgcn_global_load_lds(
        (const __attribute__((address_space(1))) void*)g,
        (__attribute__((address_space(3))) void*)lds, 16, 0, 0);
}

// fp32 rows -> bf16 frag-packed panels + fp32 row sum-of-squares; pad rows -> 0
__global__ void pack_rows_kernel(const float* __restrict__ src,
                                 unsigned short* __restrict__ dst,
                                 float* __restrict__ sq, int nrows_valid) {
    int row = blockIdx.x;
    int t = threadIdx.x;  // 256 threads, 4 consecutive floats each
    int p = row >> 4, m = row & 15;
    float s = 0.f;
    ushort4 o = make_ushort4(0, 0, 0, 0);
    if (row < nrows_valid) {
        float4 v = ((const float4*)(src + (size_t)row * D_DIM))[t];
        s = v.x * v.x + v.y * v.y + v.z * v.z + v.w * v.w;
        o.x = f2bf(v.x); o.y = f2bf(v.y); o.z = f2bf(v.z); o.w = f2bf(v.w);
    }
    size_t obase = (size_t)p * PANEL_X + (size_t)(t >> 3) * 512
                 + (size_t)((t >> 1) & 3) * 128 + m * 8 + (t & 1) * 4;
    *(ushort4*)(dst + obase) = o;
    __shared__ float red[4];
    for (int off = 32; off; off >>= 1) s += __shfl_down(s, off, 64);
    if ((t & 63) == 0) red[t >> 6] = s;
    __syncthreads();
    if (t == 0) sq[row] = red[0] + red[1] + red[2] + red[3];
}

// W [M][Y] fp32 -> frag-packed WTp; pad m>=M_CENT -> 0
__global__ void pack_wT_kernel(const float* __restrict__ w,
                               unsigned short* __restrict__ wTp) {
    __shared__ float tile[32][33];
    int m0 = blockIdx.x * 32;
    int y0 = blockIdx.y * 32;
    int tx = threadIdx.x & 31;
    int ty = threadIdx.x >> 5;
    #pragma unroll
    for (int i = 0; i < 4; ++i) {
        int mm = m0 + ty + i * 8;
        float v = (mm < M_CENT) ? w[(size_t)mm * Y_DIM + y0 + tx] : 0.f;
        tile[tx][ty + i * 8] = v;
    }
    __syncthreads();
    #pragma unroll
    for (int i = 0; i < 4; ++i) {
        int yl = ty + i * 8;
        int p = (y0 >> 4) + (yl >> 4);
        size_t off = (size_t)p * PANEL_W + (size_t)(m0 >> 5) * 512
                   + (size_t)(tx >> 3) * 128 + (yl & 15) * 8 + (tx & 7);
        wTp[off] = f2bf(tile[yl][tx]);
    }
}

// Fused kernel, R6: X deduped via LDS group-staging (8 kt = 32KB per group,
// one barrier-pair per group = 8 barriers/mt); Z and W stay register-direct
// with cross-barrier prefetch (drains at group barriers land when needed).
// A-frag bytes per lane are bit-identical to R5 (numerics unchanged).
// LDS = x_stage 32KB + lds_p 32KB (XOR-swizzled, uniform 8-cyc reads) = 64KB.
__global__ void __launch_bounds__(256, 2)
fused_kernel(const unsigned short* __restrict__ Xp,
             const unsigned short* __restrict__ Zp,
             const unsigned short* __restrict__ WTp,
             const float* __restrict__ xsq,
             const float* __restrict__ zsq,
             const int* __restrict__ bwp,
             float* __restrict__ out) {
    __shared__ unsigned short x_stage[BM * 256];  // 32 KB: [ktl][it][l16*32+quad*8+j]
    __shared__ unsigned short lds_p[BM * BN];     // 32 KB, chunk-swizzled

    const int t    = threadIdx.x;
    const int wave = t >> 6;
    const int lane = t & 63;
    const int quad = lane >> 4;
    const int l16  = lane & 15;
    const int lane8 = lane * 8;

    const int row0 = blockIdx.x * BM;
    int mt = blockIdx.y * TILES_PER_SPLIT;
    int mt_end = mt + TILES_PER_SPLIT;
    if (mt_end > M_TILES) mt_end = M_TILES;

    int bwi = *bwp;
    float bw;
    if (bwi > 0 && bwi < 1000000) bw = (float)bwi;
    else { union { int i; float f; } u; u.i = bwi; bw = u.f; }
    const float inv_bw = 1.0f / bw;

    // xsq in registers (replaces lds_xsq; LDS is exactly full)
    float xsqv[16];
    #pragma unroll
    for (int i = 0; i < 16; ++i)
        xsqv[i] = xsq[row0 + (i >> 2) * 16 + quad * 4 + (i & 3)];

    // staging-source decomposition for this thread (one ktl per gll16 iter)
    const int s_it  = t >> 6;
    const int s_l16 = (t & 63) >> 2;
    const int s_quad = t & 3;
    const unsigned short* xsrc = Xp + (size_t)((row0 >> 4) + s_it) * PANEL_X
                               + s_quad * 128 + s_l16 * 8;

    const f32x4 vzero = {0.f, 0.f, 0.f, 0.f};
    f32x4 Oacc[16];
    #pragma unroll
    for (int i = 0; i < 16; ++i) Oacc[i] = vzero;

    #pragma unroll 1
    for (; mt < mt_end; ++mt) {
        const unsigned short* zp0 = Zp + (size_t)(mt * 16 + wave * 4) * PANEL_X + lane8;

        float zqv[4];
        #pragma unroll
        for (int jt = 0; jt < 4; ++jt)
            zqv[jt] = zsq[mt * BN + wave * 64 + jt * 16 + l16];

        f32x4 S[16];
        #pragma unroll
        for (int i = 0; i < 16; ++i) S[i] = vzero;

        bf16x8 ae[4], ao[4], be[4], bo[4];
        // Z prefetch for kt=0 (drains at g=0's second barrier — lands in time)
        #pragma unroll
        for (int j = 0; j < 4; ++j)
            be[j] = *(const bf16x8*)(zp0 + (size_t)j * PANEL_X);

        // -------- Phase 1: S[64x256] = X * Z^T --------
        #pragma unroll 1
        for (int g = 0; g < NG; ++g) {
            __syncthreads();   // all waves done reading prev group's x_stage
            // stage X group g: 32 KB via async DMA (8 gll16/thread, 1 ktl each)
            const unsigned short* xg = xsrc + (size_t)(g * GKT) * 512;
            #pragma unroll
            for (int i = 0; i < GKT; ++i)
                gll16(&x_stage[(i * 256 + t) * 8], xg + (size_t)i * 512);
            __syncthreads();   // vmcnt(0): staging (and Z prefetch) landed
            // A frags for ktl=0
            #pragma unroll
            for (int i = 0; i < 4; ++i)
                ae[i] = *(const bf16x8*)&x_stage[i * 512 + l16 * 32 + quad * 8];

            #pragma unroll
            for (int kp = 0; kp < GKT / 2; ++kp) {
                const int kt = g * GKT + kp * 2;
                // --- even: compute (ae,be), prefetch (ao,bo) for kt+1 ---
                #pragma unroll
                for (int i = 0; i < 4; ++i)
                    ao[i] = *(const bf16x8*)&x_stage[(kp * 2 + 1) * 2048
                                                     + i * 512 + l16 * 32 + quad * 8];
                {
                    const unsigned short* zk = zp0 + (size_t)(kt + 1) * 512;
                    #pragma unroll
                    for (int j = 0; j < 4; ++j)
                        bo[j] = *(const bf16x8*)(zk + (size_t)j * PANEL_X);
                }
                #pragma unroll
                for (int it = 0; it < 4; ++it)
                    #pragma unroll
                    for (int jt = 0; jt < 4; ++jt)
                        S[it * 4 + jt] = __builtin_amdgcn_mfma_f32_16x16x32_bf16(
                            ae[it], be[jt], S[it * 4 + jt], 0, 0, 0);
                // --- odd: compute (ao,bo), prefetch (ae,be) for kt+2 ---
                if (kp < GKT / 2 - 1) {   // A for next ktl in this group
                    #pragma unroll
                    for (int i = 0; i < 4; ++i)
                        ae[i] = *(const bf16x8*)&x_stage[(kp * 2 + 2) * 2048
                                                         + i * 512 + l16 * 32 + quad * 8];
                }
                {   // Z for kt+2 (may cross group boundary; overrun at the very
                    // last kt reads adjacent ws — harmless, discarded)
                    const unsigned short* zk = zp0 + (size_t)(kt + 2) * 512;
                    #pragma unroll
                    for (int j = 0; j < 4; ++j)
                        be[j] = *(const bf16x8*)(zk + (size_t)j * PANEL_X);
                }
                #pragma unroll
                for (int it = 0; it < 4; ++it)
                    #pragma unroll
                    for (int jt = 0; jt < 4; ++jt)
                        S[it * 4 + jt] = __builtin_amdgcn_mfma_f32_16x16x32_bf16(
                            ao[it], bo[jt], S[it * 4 + jt], 0, 0, 0);
            }
        }

        // -------- Phase 2: P = exp(-sqrt(d2)/bw) -> lds_p (swizzled bf16) ----
        // No barrier needed before writes: every wave passed the g-loop
        // barriers, so prev mt's Phase-3 reads of lds_p are complete.
        #pragma unroll
        for (int it = 0; it < 4; ++it) {
            #pragma unroll
            for (int jt = 0; jt < 4; ++jt) {
                f32x4 s4 = S[it * 4 + jt];
                const int col = wave * 64 + jt * 16 + l16;
                const int ch0 = col >> 3, cl = col & 7;
                const float zq = zqv[jt];
                #pragma unroll
                for (int r = 0; r < 4; ++r) {
                    const int row = it * 16 + quad * 4 + r;   // C-layout
                    float d2 = xsqv[it * 4 + r] + zq - 2.0f * s4[r];
                    d2 = fmaxf(d2, 0.f);
                    float p = __expf(-sqrtf(d2) * inv_bw);
                    lds_p[row * 256 + ((ch0 ^ (row & 7)) << 3) + cl] = f2bf(p);
                }
            }
        }
        __syncthreads();

        // -------- Phase 3: O += P[64x256] * Wtile[256x256] --------
        #pragma unroll
        for (int ks = 0; ks < 8; ++ks) {
            bf16x8 a[4], b[4];
            #pragma unroll
            for (int rt = 0; rt < 4; ++rt) {
                const int row = rt * 16 + l16;     // row&7 == l16&7
                a[rt] = *(const bf16x8*)&lds_p[row * 256
                          + (((ks * 4 + quad) ^ (l16 & 7)) << 3)];
            }
            #pragma unroll
            for (int ct = 0; ct < 4; ++ct)
                b[ct] = *(const bf16x8*)(WTp + (size_t)(wave * 4 + ct) * PANEL_W
                                             + (size_t)(mt * 8 + ks) * 512 + lane8);
            #pragma unroll
            for (int rt = 0; rt < 4; ++rt)
                #pragma unroll
                for (int ct = 0; ct < 4; ++ct)
                    Oacc[rt * 4 + ct] = __builtin_amdgcn_mfma_f32_16x16x32_bf16(
                        a[rt], b[ct], Oacc[rt * 4 + ct], 0, 0, 0);
        }
    }

    // -------- epilogue: accumulate M-splits via device-scope fp32 atomics ----
    #pragma unroll
    for (int rt = 0; rt < 4; ++rt) {
        #pragma unroll
        for (int ct = 0; ct < 4; ++ct) {
            f32x4 v = Oacc[rt * 4 + ct];
            const int y = wave * 64 + ct * 16 + l16;
            #pragma unroll
            for (int r = 0; r < 4; ++r) {
                const int row = row0 + rt * 16 + quad * 4 + r;
                atomicAdd(&out[(size_t)row * Y_DIM + y], v[r]);
            }
        }
    }
}

extern "C" void kernel_launch(void* const* d_in, const int* in_sizes, int n_in,
                              void* d_out, int out_size, void* d_ws, size_t ws_size,
                              hipStream_t stream) {
    const float* X = (const float*)d_in[0];
    const float* Z = (const float*)d_in[1];
    const float* W = (const float*)d_in[2];
    const int*  bw = (const int*)d_in[3];
    float* out = (float*)d_out;

    char* ws = (char*)d_ws;
    size_t off = 0;
    unsigned short* Xp  = (unsigned short*)(ws + off); off += (size_t)N_ROWS * D_DIM * 2;
    unsigned short* Zp  = (unsigned short*)(ws + off); off += (size_t)M_PAD * D_DIM * 2;
    unsigned short* WTp = (unsigned short*)(ws + off); off += (size_t)Y_DIM * M_PAD * 2;
    float* xsq = (float*)(ws + off); off += (size_t)N_ROWS * 4;
    float* zsq = (float*)(ws + off); off += (size_t)M_PAD * 4;
    // total ws use: ~67.9 MB (+prefetch-overrun slack stays inside ws)

    hipMemsetAsync(d_out, 0, (size_t)out_size * sizeof(float), stream);
    pack_rows_kernel<<<N_ROWS, 256, 0, stream>>>(X, Xp, xsq, N_ROWS);
    pack_rows_kernel<<<M_PAD, 256, 0, stream>>>(Z, Zp, zsq, M_CENT);
    pack_wT_kernel<<<dim3(M_PAD / 32, Y_DIM / 32), 256, 0, stream>>>(W, WTp);
    fused_kernel<<<dim3(N_ROWS / BM, MSPLIT), 256, 0, stream>>>(Xp, Zp, WTp, xsq, zsq, bw, out);
}